// Round 1
// 225.893 us; speedup vs baseline: 1.3247x; 1.3247x over previous
//
#include <hip/hip_runtime.h>

// BEV transformer block, MI355X/gfx950.  Round 6: k_attn LDS round-trip removed.
// QK^T computed SWAPPED (mfma(K,Q) -> S^T), P transposed to PV B-frag fully
// in-register via v_cvt_pk_bf16_f32 + v_permlane{32,16}_swap_b32 (T12).
// k_attn now uses zero LDS; bias permutation in k_prep swapped to match.
// ws layout (bytes) — regions aliased across kernel lifetimes (peak 53,084,160):
//   [0,10485760)          Xw (k_prep..k_qkv)  then AO (k_attn..k_out_ln)
//   [10485760,11534336)   bf16 weights (all)
//   [11534336,42991616)   Qb/Kb/VbT (k_qkv..k_attn); then Yn (k_out_ln..k_fc1) @22020096
//   [42991616,49545216)   biasPh bf16 C-frag-permuted (k_prep..k_attn)
//   [32505856,53084160)   G (k_fc1..k_fc2) — overlaps VbT/biasPh, disjoint lifetime

using f32x4 = __attribute__((ext_vector_type(4))) float;
using s16x8 = __attribute__((ext_vector_type(8))) short;
using u32x4 = __attribute__((ext_vector_type(4))) unsigned;

__device__ __forceinline__ ushort f2b(float f) {            // RNE (cold paths)
  union { float f; unsigned u; } v; v.f = f;
  return (ushort)((v.u + 0x7FFFu + ((v.u >> 16) & 1u)) >> 16);
}
__device__ __forceinline__ ushort f2b_fast(float f) {       // round-half-up
  union { float f; unsigned u; } v; v.f = f;
  return (ushort)((v.u + 0x8000u) >> 16);
}
__device__ __forceinline__ float b2f(ushort u) {
  union { unsigned u; float f; } v; v.u = ((unsigned)u) << 16; return v.f;
}
__device__ __forceinline__ float lo2f(unsigned w) {
  union { unsigned u; float f; } v; v.u = w << 16; return v.f;
}
__device__ __forceinline__ float hi2f(unsigned w) {
  union { unsigned u; float f; } v; v.u = w & 0xffff0000u; return v.f;
}

__device__ __forceinline__ unsigned cvtpk(float lo, float hi) {
  unsigned r;
  asm("v_cvt_pk_bf16_f32 %0, %1, %2" : "=v"(r) : "v"(lo), "v"(hi));
  return r;
}
// D[32:63] <-> S[0:31]:  a' = {a[0:31] | b[0:31]},  b' = {a[32:63] | b[32:63]}
__device__ __forceinline__ void pl32(unsigned& a, unsigned& b) {
  asm("v_permlane32_swap_b32 %0, %1" : "+v"(a), "+v"(b));
}
// odd 16-rows of D <-> even 16-rows of S:
// a' = {a[0:15], b[0:15], a[32:47], b[32:47]},  b' = {a[16:31], b[16:31], a[48:63], b[48:63]}
__device__ __forceinline__ void pl16(unsigned& a, unsigned& b) {
  asm("v_permlane16_swap_b32 %0, %1" : "+v"(a), "+v"(b));
}

__device__ __forceinline__ void gld16(const void* g, void* l) {
  __builtin_amdgcn_global_load_lds((const __attribute__((address_space(1))) void*)g,
                                   (__attribute__((address_space(3))) void*)l, 16, 0, 0);
}

// ---------------- shared 128x128 MFMA GEMM core ----------------
template<int KB>
__device__ __forceinline__ void gemm_core(const ushort* __restrict__ A, int lda,
                                          const ushort* __restrict__ B, int ldb,
                                          f32x4 acc[4][4]) {
  __shared__ ushort As[128 * 64];
  __shared__ ushort Bs[128 * 64];
  const int tid = threadIdx.x;
  const int lane = tid & 63;
  const int wv = tid >> 6;
  const int wr = (wv >> 1) * 64;
  const int wc = (wv & 1) * 64;
  const int srow = (lane >> 3);
  const int sg = ((lane & 7) ^ (srow & 7)) * 8;
  f32x4 zero = {0.f, 0.f, 0.f, 0.f};
#pragma unroll
  for (int mt = 0; mt < 4; ++mt)
#pragma unroll
    for (int nt = 0; nt < 4; ++nt) acc[mt][nt] = zero;

  for (int kb = 0; kb < KB; ++kb) {
#pragma unroll
    for (int j = 0; j < 4; ++j) {
      int r0 = wv * 32 + j * 8;
      int row = r0 + srow;
      gld16(A + row * lda + kb * 64 + sg, &As[r0 * 64]);
      gld16(B + row * ldb + kb * 64 + sg, &Bs[r0 * 64]);
    }
    __syncthreads();
#pragma unroll
    for (int ks = 0; ks < 2; ++ks) {
      s16x8 af[4], bfr[4];
      const int G = ks * 4 + (lane >> 4);
#pragma unroll
      for (int mt = 0; mt < 4; ++mt) {
        int row = wr + mt * 16 + (lane & 15);
        af[mt] = *(const s16x8*)&As[row * 64 + (G ^ (row & 7)) * 8];
      }
#pragma unroll
      for (int nt = 0; nt < 4; ++nt) {
        int row = wc + nt * 16 + (lane & 15);
        bfr[nt] = *(const s16x8*)&Bs[row * 64 + (G ^ (row & 7)) * 8];
      }
#pragma unroll
      for (int mt = 0; mt < 4; ++mt)
#pragma unroll
        for (int nt = 0; nt < 4; ++nt)
          acc[mt][nt] = __builtin_amdgcn_mfma_f32_16x16x32_bf16(af[mt], bfr[nt], acc[mt][nt], 0, 0, 0);
    }
    __syncthreads();
  }
}

// ---------------- kernel 1: gather + weight casts + permuted bias build ----------------
__global__ __launch_bounds__(256) void k_prep(const float* __restrict__ x,
                                              const float* __restrict__ wqkv,
                                              const float* __restrict__ wout,
                                              const float* __restrict__ w1,
                                              const float* __restrict__ w2,
                                              const float* __restrict__ table,
                                              ushort* __restrict__ Xw,
                                              ushort* __restrict__ wqkvb,
                                              ushort* __restrict__ woutb,
                                              ushort* __restrict__ w1b,
                                              ushort* __restrict__ w2b,
                                              ushort* __restrict__ biasPh) {
  __shared__ ushort smem[64 * 264];
  const int bid = blockIdx.x, tid = threadIdx.x;
  if (bid < 320) {
    ushort (*Ls)[264] = (ushort(*)[264])smem;
    const int t0 = bid * 64;
    const int w = t0 / 640;
    const int tokbase = t0 - w * 640;
    const int b = w >> 4, wh = (w >> 2) & 3, ww = w & 3;
    for (int i = tid; i < 64 * 256; i += 256) {
      int c = i >> 6, tl = i & 63;
      int tok = tokbase + tl;
      ushort val = 0;
      if (tok < 625) {
        int ii = tok / 25, jj = tok - ii * 25;
        val = f2b(x[((b * 256 + c) * 100 + wh * 25 + ii) * 100 + ww * 25 + jj]);
      }
      Ls[tl][c] = val;
    }
    __syncthreads();
    for (int i = tid; i < 64 * 32; i += 256) {
      int tl = i >> 5, g = (i & 31) * 8;
      *(uint4*)(Xw + (t0 + tl) * 256 + g) = *(const uint4*)&Ls[tl][g];
    }
  } else if (bid < 832) {
    int v = (bid - 320) * 1024 + tid * 4;
    const float* src; ushort* dst; int off;
    if (v < 196608)      { src = wqkv; dst = wqkvb; off = v; }
    else if (v < 262144) { src = wout; dst = woutb; off = v - 196608; }
    else if (v < 393216) { src = w1;   dst = w1b;   off = v - 262144; }
    else                 { src = w2;   dst = w2b;   off = v - 393216; }
    float4 f = *(const float4*)(src + off);
    ushort4 u; u.x = f2b(f.x); u.y = f2b(f.y); u.z = f2b(f.z); u.w = f2b(f.w);
    *(ushort4*)(dst + off) = u;
  } else {
    // bias permuted to SWAPPED attn C-frag order (S^T: rows=kv, cols=q),
    // *log2e, kv-mask folded in.  C-frag: lane(quad,cl) reg rr holds
    // C[kv = chunk*16 + quad*4+rr][q = t*16 + cl].
    float* tl = (float*)smem;
    const int qb = bid - 832;
    const int h = qb / 40, t = qb - (qb / 40) * 40;
    for (int i = tid; i < 2401; i += 256) tl[i] = table[i * 8 + h] * 1.4426950408889634f;
    __syncthreads();
    const int lane = tid >> 2, rr = tid & 3;
    const int quad = lane >> 4, cl = lane & 15;
    int qrow = t * 16 + cl;
    int qg = (qrow < 625) ? qrow : 0;
    const int ri = qg / 25, ci = qg - ri * 25;
    for (int cc = 0; cc < 4; ++cc)
      for (int cp = 0; cp < 5; ++cp)
#pragma unroll
        for (int codd = 0; codd < 2; ++codd) {
          int kv = cc * 160 + (cp * 2 + codd) * 16 + quad * 4 + rr;
          float v = -1e30f;
          if (kv < 625) {
            int rj = kv / 25, cj = kv - rj * 25;
            v = tl[(ri - rj + 24) * 49 + (ci - cj + 24)];
          }
          biasPh[((((h * 40 + t) * 4 + cc) * 5 + cp) * 64 + lane) * 8 + codd * 4 + rr] = f2b(v);
        }
  }
}

// ---------------- kernel 2: QKV projection ----------------
__global__ __launch_bounds__(256) void k_qkv(const ushort* __restrict__ Xw,
                                             const ushort* __restrict__ Wb,
                                             ushort* __restrict__ Qb,
                                             ushort* __restrict__ Kb,
                                             ushort* __restrict__ VbT) {
  f32x4 acc[4][4];
  gemm_core<4>(Xw + blockIdx.x * 128 * 256, 256, Wb + blockIdx.y * 128 * 256, 256, acc);
  const int lane = threadIdx.x & 63, wv = threadIdx.x >> 6;
  const int wr = (wv >> 1) * 64, wc = (wv & 1) * 64;
  const int which = blockIdx.y >> 1;
  const float QSC = 0.17677669529663687f * 1.4426950408889634f;
#pragma unroll
  for (int mt = 0; mt < 4; ++mt) {
#pragma unroll
    for (int nt = 0; nt < 4; ++nt) {
      int n = blockIdx.y * 128 + wc + nt * 16 + (lane & 15);
      int h = (n >> 5) & 7, ch = n & 31;
      int m0 = blockIdx.x * 128 + wr + mt * 16 + (lane >> 4) * 4;
      int w = m0 / 640, tok0 = m0 - w * 640;
      if (which == 2) {
        ushort4 pk;
        pk.x = f2b_fast(acc[mt][nt][0]); pk.y = f2b_fast(acc[mt][nt][1]);
        pk.z = f2b_fast(acc[mt][nt][2]); pk.w = f2b_fast(acc[mt][nt][3]);
        *(ushort4*)(VbT + (((w << 3) + h) * 32 + ch) * 640 + tok0) = pk;
      } else {
        ushort* dst = which == 0 ? Qb : Kb;
        float sc = which == 0 ? QSC : 1.f;
#pragma unroll
        for (int r = 0; r < 4; ++r)
          dst[(((w << 3) + h) * 640 + tok0 + r) * 32 + ch] = f2b_fast(acc[mt][nt][r] * sc);
      }
    }
  }
}

// ---------------- kernel 3: fused windowed attention — zero-LDS, in-register P ----------------
// 1280 blocks = 32win x 5tg x 8h (h=bid&7 XCD pin). Each wave owns q-tiles
// t0=tg*8+wv*2 and t0+1, sharing K and V fragments.
// QK^T computed SWAPPED: s = mfma(K, Q, biasT) -> S^T (rows kv, cols q).
// Identical Q/K/V load addresses as before (A/B frag patterns coincide).
// P -> PV B-frag via cvt_pk_bf16 + permlane32_swap + permlane16_swap:
//   per kc: E=2kc,O=2kc+1; pl32+pl16 on (E.w0,O.w0) -> frag words 0,2;
//   same on (E.w1,O.w1) -> words 1,3.  No LDS, no syncthreads anywhere.
// Row-sums via ones-MFMA (A=ones, B=P: every C row = per-column kv-sum).
// Output is o^T: lane holds 4 consecutive channels -> ushort4 stores.
__global__ __launch_bounds__(256, 3) void k_attn(const ushort* __restrict__ Qb,
                                                 const ushort* __restrict__ Kb,
                                                 const ushort* __restrict__ VbT,
                                                 const ushort* __restrict__ biasPh,
                                                 ushort* __restrict__ AO) {
  const int tid = threadIdx.x;
  const int lane = tid & 63;
  const int wv = tid >> 6;
  const int quad = lane >> 4;
  const int cl = lane & 15;
  const int bid = blockIdx.x;
  const int h = bid & 7;                // XCD pin
  const int rem = bid >> 3;             // 0..159
  const int win = rem / 5;
  const int tg = rem - win * 5;
  const ushort* Qg = Qb + (win * 8 + h) * 20480;
  const ushort* Kg = Kb + (win * 8 + h) * 20480;
  const ushort* Vt = VbT + (win * 8 + h) * 20480;   // [ch][640]

  const int t0 = tg * 8 + wv * 2;
  const s16x8 qf0 = *(const s16x8*)(Qg + (t0 * 16 + cl) * 32 + quad * 8);
  const s16x8 qf1 = *(const s16x8*)(Qg + ((t0 + 1) * 16 + cl) * 32 + quad * 8);
  s16x8 ones;
#pragma unroll
  for (int j = 0; j < 8; ++j) ones[j] = (short)0x3F80;    // bf16 1.0

  const f32x4 zero = {0.f, 0.f, 0.f, 0.f};
  f32x4 o00 = zero, o01 = zero, o10 = zero, o11 = zero;
  f32x4 sum0 = zero, sum1 = zero;

#pragma unroll
  for (int cc = 0; cc < 4; ++cc) {
    // --- prefetch: K frags (A-operand of S^T), V frags (A-operand of o^T) ---
    s16x8 kf[10];
#pragma unroll
    for (int c = 0; c < 10; ++c)
      kf[c] = *(const s16x8*)(Kg + (cc * 160 + c * 16 + cl) * 32 + quad * 8);
    s16x8 vf0[5], vf1[5];
#pragma unroll
    for (int kc = 0; kc < 5; ++kc) {
      vf0[kc] = *(const s16x8*)(Vt + cl * 640 + cc * 160 + kc * 32 + quad * 8);
      vf1[kc] = *(const s16x8*)(Vt + (16 + cl) * 640 + cc * 160 + kc * 32 + quad * 8);
    }
#pragma unroll
    for (int tlp = 0; tlp < 2; ++tlp) {
      const int t = t0 + tlp;
      const s16x8 qf = tlp ? qf1 : qf0;
      // --- bias as MFMA C-operand (log2-domain, kv-mask folded, S^T order) ---
      const ushort* bp = biasPh + (((h * 40 + t) * 4 + cc) * 5) * 512 + lane * 8;
      f32x4 s[10];
#pragma unroll
      for (int cp = 0; cp < 5; ++cp) {
        s16x8 bb = *(const s16x8*)(bp + cp * 512);
        const unsigned* bw = (const unsigned*)&bb;
        f32x4 c0, c1;
        c0[0] = lo2f(bw[0]); c0[1] = hi2f(bw[0]); c0[2] = lo2f(bw[1]); c0[3] = hi2f(bw[1]);
        c1[0] = lo2f(bw[2]); c1[1] = hi2f(bw[2]); c1[2] = lo2f(bw[3]); c1[3] = hi2f(bw[3]);
        s[cp * 2] = c0; s[cp * 2 + 1] = c1;
      }
      // --- S^T = K·Q^T + bias (swapped operands; loads unchanged) ---
#pragma unroll
      for (int c = 0; c < 10; ++c)
        s[c] = __builtin_amdgcn_mfma_f32_16x16x32_bf16(kf[c], qf, s[c], 0, 0, 0);
      // --- exp2 in place (no max: scores small, mask via -1e30) ---
#pragma unroll
      for (int c = 0; c < 10; ++c)
#pragma unroll
        for (int r = 0; r < 4; ++r) s[c][r] = exp2f(s[c][r]);
      // --- in-register transpose to PV B-frag + PV + ones-sum ---
      f32x4& o0 = tlp ? o10 : o00;
      f32x4& o1 = tlp ? o11 : o01;
      f32x4& sm = tlp ? sum1 : sum0;
#pragma unroll
      for (int kc = 0; kc < 5; ++kc) {
        unsigned a0 = cvtpk(s[2 * kc][0], s[2 * kc][1]);
        unsigned a1 = cvtpk(s[2 * kc][2], s[2 * kc][3]);
        unsigned b0 = cvtpk(s[2 * kc + 1][0], s[2 * kc + 1][1]);
        unsigned b1 = cvtpk(s[2 * kc + 1][2], s[2 * kc + 1][3]);
        pl32(a0, b0); pl16(a0, b0);       // a0 -> frag word0, b0 -> word2
        pl32(a1, b1); pl16(a1, b1);       // a1 -> word1,      b1 -> word3
        u32x4 pw; pw[0] = a0; pw[1] = a1; pw[2] = b0; pw[3] = b1;
        s16x8 pf = __builtin_bit_cast(s16x8, pw);
        o0 = __builtin_amdgcn_mfma_f32_16x16x32_bf16(vf0[kc], pf, o0, 0, 0, 0);
        o1 = __builtin_amdgcn_mfma_f32_16x16x32_bf16(vf1[kc], pf, o1, 0, 0, 0);
        sm = __builtin_amdgcn_mfma_f32_16x16x32_bf16(ones, pf, sm, 0, 0, 0);
      }
    }
  }
  // --- normalize + store; o^T rows = channels, cols = q (lane-local sum) ---
#pragma unroll
  for (int tlp = 0; tlp < 2; ++tlp) {
    const f32x4& o0 = tlp ? o10 : o00;
    const f32x4& o1 = tlp ? o11 : o01;
    const f32x4& sm = tlp ? sum1 : sum0;
    int tok = (t0 + tlp) * 16 + cl;
    if (tok < 625) {
      float inv = 1.f / sm[0];
      int base = (win * 640 + tok) * 256 + h * 32 + quad * 4;
      ushort4 p0, p1;
      p0.x = f2b_fast(o0[0] * inv); p0.y = f2b_fast(o0[1] * inv);
      p0.z = f2b_fast(o0[2] * inv); p0.w = f2b_fast(o0[3] * inv);
      p1.x = f2b_fast(o1[0] * inv); p1.y = f2b_fast(o1[1] * inv);
      p1.z = f2b_fast(o1[2] * inv); p1.w = f2b_fast(o1[3] * inv);
      *(ushort4*)(AO + base) = p0;
      *(ushort4*)(AO + base + 16) = p1;
    }
  }
}

// ---------------- kernel 4: out-projection + un-partition + LayerNorm ----------------
__global__ __launch_bounds__(256, 2) void k_out_ln(const ushort* __restrict__ AO,
                                                   const ushort* __restrict__ Wb,
                                                   const float* __restrict__ gamma,
                                                   const float* __restrict__ beta,
                                                   ushort* __restrict__ Yn) {
  __shared__ ushort As[64 * 64];
  __shared__ ushort Bs[256 * 64];
  __shared__ float red[2][64][2];
  const int tid = threadIdx.x;
  const int lane = tid & 63;
  const int wv = tid >> 6;
  const int wr = (wv >> 1) * 32, wc = (wv & 1) * 128;
  const int quad = lane >> 4, cl = lane & 15;
  const int srow = lane >> 3;
  const int sg = ((lane & 7) ^ (srow & 7)) * 8;
  f32x4 zero = {0.f, 0.f, 0.f, 0.f};
  f32x4 acc[2][8];
#pragma unroll
  for (int mt = 0; mt < 2; ++mt)
#pragma unroll
    for (int nt = 0; nt < 8; ++nt) acc[mt][nt] = zero;

  const ushort* A = AO + blockIdx.x * 64 * 256;
  for (int kb = 0; kb < 4; ++kb) {
#pragma unroll
    for (int i = 0; i < 10; ++i) {
      int r0 = (wv + i * 4) * 8;
      int row = r0 + srow;
      if (r0 < 64) gld16(A + row * 256 + kb * 64 + sg, &As[r0 * 64]);
      else         gld16(Wb + (row - 64) * 256 + kb * 64 + sg, &Bs[(r0 - 64) * 64]);
    }
    __syncthreads();
#pragma unroll
    for (int ks = 0; ks < 2; ++ks) {
      s16x8 af[2], bfr[8];
      const int G = ks * 4 + quad;
#pragma unroll
      for (int mt = 0; mt < 2; ++mt) {
        int row = wr + mt * 16 + cl;
        af[mt] = *(const s16x8*)&As[row * 64 + (G ^ (row & 7)) * 8];
      }
#pragma unroll
      for (int nt = 0; nt < 8; ++nt) {
        int row = wc + nt * 16 + cl;
        bfr[nt] = *(const s16x8*)&Bs[row * 64 + (G ^ (row & 7)) * 8];
      }
#pragma unroll
      for (int mt = 0; mt < 2; ++mt)
#pragma unroll
        for (int nt = 0; nt < 8; ++nt)
          acc[mt][nt] = __builtin_amdgcn_mfma_f32_16x16x32_bf16(af[mt], bfr[nt], acc[mt][nt], 0, 0, 0);
    }
    __syncthreads();
  }
#pragma unroll
  for (int mt = 0; mt < 2; ++mt)
#pragma unroll
    for (int r = 0; r < 4; ++r) {
      float s = 0.f, ss = 0.f;
#pragma unroll
      for (int nt = 0; nt < 8; ++nt) { float v = acc[mt][nt][r]; s += v; ss += v * v; }
      s += __shfl_xor(s, 1, 64); ss += __shfl_xor(ss, 1, 64);
      s += __shfl_xor(s, 2, 64); ss += __shfl_xor(ss, 2, 64);
      s += __shfl_xor(s, 4, 64); ss += __shfl_xor(ss, 4, 64);
      s += __shfl_xor(s, 8, 64); ss += __shfl_xor(ss, 8, 64);
      if (cl == 0) {
        int row = wr + mt * 16 + quad * 4 + r;
        red[wc >> 7][row][0] = s;
        red[wc >> 7][row][1] = ss;
      }
    }
  __syncthreads();
  float g[8], bt[8];
#pragma unroll
  for (int nt = 0; nt < 8; ++nt) { int n = wc + nt * 16 + cl; g[nt] = gamma[n]; bt[nt] = beta[n]; }
  const int m0 = blockIdx.x * 64;
#pragma unroll
  for (int mt = 0; mt < 2; ++mt)
#pragma unroll
    for (int r = 0; r < 4; ++r) {
      int row = wr + mt * 16 + quad * 4 + r;
      int m = m0 + row;
      int w = m / 640, tok = m - w * 640;
      if (tok < 625) {
        float sum = red[0][row][0] + red[1][row][0];
        float ssum = red[0][row][1] + red[1][row][1];
        float mean = sum * 0.00390625f;
        float var = ssum * 0.00390625f - mean * mean;
        float rstd = rsqrtf(var + 1e-5f);
        int b = w >> 4, whh = (w >> 2) & 3, www = w & 3;
        int ii = tok / 25, jj = tok - ii * 25;
        int p = (whh * 25 + ii) * 100 + www * 25 + jj;
        ushort* dst = Yn + (b * 10000 + p) * 256;
#pragma unroll
        for (int nt = 0; nt < 8; ++nt) {
          float v = (acc[mt][nt][r] - mean) * rstd * g[nt] + bt[nt];
          dst[wc + nt * 16 + cl] = f2b_fast(v);
        }
      }
    }
}

// ---------------- kernel 5: fc1 + exact GELU ----------------
__global__ __launch_bounds__(256) void k_fc1(const ushort* __restrict__ Yn,
                                             const ushort* __restrict__ W1b,
                                             const float* __restrict__ b1,
                                             ushort* __restrict__ G) {
  f32x4 acc[4][4];
  gemm_core<4>(Yn + blockIdx.x * 128 * 256, 256, W1b + blockIdx.y * 128 * 256, 256, acc);
  const int lane = threadIdx.x & 63, wv = threadIdx.x >> 6;
  const int wr = (wv >> 1) * 64, wc = (wv & 1) * 64;
#pragma unroll
  for (int mt = 0; mt < 4; ++mt)
#pragma unroll
    for (int nt = 0; nt < 4; ++nt) {
      int n = blockIdx.y * 128 + wc + nt * 16 + (lane & 15);
      float bias = b1[n];
#pragma unroll
      for (int r = 0; r < 4; ++r) {
        int m = blockIdx.x * 128 + wr + mt * 16 + (lane >> 4) * 4 + r;
        float v = acc[mt][nt][r] + bias;
        v = 0.5f * v * (1.f + erff(v * 0.70710678118f));
        G[m * 512 + n] = f2b_fast(v);
      }
    }
}

// ---------------- kernel 6: fc2 + residual, swapped roles (M=ch, N=tok) ----------------
__global__ __launch_bounds__(256) void k_fc2(const ushort* __restrict__ W2b,
                                             const ushort* __restrict__ G,
                                             const float* __restrict__ b2,
                                             const float* __restrict__ x,
                                             float* __restrict__ out) {
  f32x4 acc[4][4];
  gemm_core<8>(W2b + blockIdx.x * 128 * 512, 512, G + blockIdx.y * 128 * 512, 512, acc);
  const int lane = threadIdx.x & 63, wv = threadIdx.x >> 6;
  const int wr = (wv >> 1) * 64, wc = (wv & 1) * 64;
#pragma unroll
  for (int mt = 0; mt < 4; ++mt)
#pragma unroll
    for (int nt = 0; nt < 4; ++nt) {
      int t = blockIdx.y * 128 + wc + nt * 16 + (lane & 15);
      if (t < 20000) {
        int b = t / 10000, p = t - b * 10000;
#pragma unroll
        for (int r = 0; r < 4; ++r) {
          int c = blockIdx.x * 128 + wr + mt * 16 + (lane >> 4) * 4 + r;
          int idx = (b * 256 + c) * 10000 + p;
          out[idx] = x[idx] + acc[mt][nt][r] + b2[c];
        }
      }
    }
}

extern "C" void kernel_launch(void* const* d_in, const int* in_sizes, int n_in,
                              void* d_out, int out_size, void* d_ws, size_t ws_size,
                              hipStream_t stream) {
  const float* x     = (const float*)d_in[0];
  const float* wqkv  = (const float*)d_in[1];
  const float* wout  = (const float*)d_in[2];
  const float* bias  = (const float*)d_in[3];
  const float* gamma = (const float*)d_in[4];
  const float* beta  = (const float*)d_in[5];
  const float* w1    = (const float*)d_in[6];
  const float* b1    = (const float*)d_in[7];
  const float* w2    = (const float*)d_in[8];
  const float* b2    = (const float*)d_in[9];
  float* out = (float*)d_out;
  char* ws = (char*)d_ws;

  ushort* Xw    = (ushort*)(ws + 0);
  ushort* AO    = Xw;
  ushort* wqkvb = (ushort*)(ws + 10485760);
  ushort* woutb = (ushort*)(ws + 10878976);
  ushort* w1b   = (ushort*)(ws + 11010048);
  ushort* w2b   = (ushort*)(ws + 11272192);
  ushort* Qb    = (ushort*)(ws + 11534336);
  ushort* Kb    = (ushort*)(ws + 22020096);
  ushort* VbT   = (ushort*)(ws + 32505856);
  ushort* biasPh= (ushort*)(ws + 42991616);
  ushort* Yn    = (ushort*)(ws + 22020096);
  ushort* G     = (ushort*)(ws + 32505856);

  k_prep  <<<1152, 256, 0, stream>>>(x, wqkv, wout, w1, w2, bias,
                                     Xw, wqkvb, woutb, w1b, w2b, biasPh);
  k_qkv   <<<dim3(160, 6), 256, 0, stream>>>(Xw, wqkvb, Qb, Kb, VbT);
  k_attn  <<<1280, 256, 0, stream>>>(Qb, Kb, VbT, biasPh, AO);
  k_out_ln<<<320, 256, 0, stream>>>(AO, woutb, gamma, beta, Yn);
  k_fc1   <<<dim3(157, 4), 256, 0, stream>>>(Yn, w1b, b1, G);
  k_fc2   <<<dim3(2, 157), 256, 0, stream>>>(w2b, G, b2, x, out);
}

// Round 2
// 223.529 us; speedup vs baseline: 1.3388x; 1.0106x over previous
//
#include <hip/hip_runtime.h>

// BEV transformer block, MI355X/gfx950.  Round 7: k_attn register-pressure fix.
// R6 post-mortem: occupancy stuck at ~25% (2 waves/SIMD) — unified VGPR+AGPR
// file holds ~170 regs (10 K-frags + 10 V-frags + 10 score accs live).
// R7: depth-first per-kc restructure (2 K-frags, 2 V-frags, 2 score accs live),
// __launch_bounds__(256,4), raw v_exp_f32 via __builtin_amdgcn_exp2f.
// ws layout (bytes) — regions aliased across kernel lifetimes (peak 53,084,160):
//   [0,10485760)          Xw (k_prep..k_qkv)  then AO (k_attn..k_out_ln)
//   [10485760,11534336)   bf16 weights (all)
//   [11534336,42991616)   Qb/Kb/VbT (k_qkv..k_attn); then Yn (k_out_ln..k_fc1) @22020096
//   [42991616,49545216)   biasPh bf16 C-frag-permuted (k_prep..k_attn)
//   [32505856,53084160)   G (k_fc1..k_fc2) — overlaps VbT/biasPh, disjoint lifetime

using f32x4 = __attribute__((ext_vector_type(4))) float;
using s16x8 = __attribute__((ext_vector_type(8))) short;
using u32x4 = __attribute__((ext_vector_type(4))) unsigned;

__device__ __forceinline__ ushort f2b(float f) {            // RNE (cold paths)
  union { float f; unsigned u; } v; v.f = f;
  return (ushort)((v.u + 0x7FFFu + ((v.u >> 16) & 1u)) >> 16);
}
__device__ __forceinline__ ushort f2b_fast(float f) {       // round-half-up
  union { float f; unsigned u; } v; v.f = f;
  return (ushort)((v.u + 0x8000u) >> 16);
}
__device__ __forceinline__ float b2f(ushort u) {
  union { unsigned u; float f; } v; v.u = ((unsigned)u) << 16; return v.f;
}
__device__ __forceinline__ float lo2f(unsigned w) {
  union { unsigned u; float f; } v; v.u = w << 16; return v.f;
}
__device__ __forceinline__ float hi2f(unsigned w) {
  union { unsigned u; float f; } v; v.u = w & 0xffff0000u; return v.f;
}

__device__ __forceinline__ unsigned cvtpk(float lo, float hi) {
  unsigned r;
  asm("v_cvt_pk_bf16_f32 %0, %1, %2" : "=v"(r) : "v"(lo), "v"(hi));
  return r;
}
// D[32:63] <-> S[0:31]:  a' = {a[0:31] | b[0:31]},  b' = {a[32:63] | b[32:63]}
__device__ __forceinline__ void pl32(unsigned& a, unsigned& b) {
  asm("v_permlane32_swap_b32 %0, %1" : "+v"(a), "+v"(b));
}
// odd 16-rows of D <-> even 16-rows of S
__device__ __forceinline__ void pl16(unsigned& a, unsigned& b) {
  asm("v_permlane16_swap_b32 %0, %1" : "+v"(a), "+v"(b));
}

__device__ __forceinline__ void gld16(const void* g, void* l) {
  __builtin_amdgcn_global_load_lds((const __attribute__((address_space(1))) void*)g,
                                   (__attribute__((address_space(3))) void*)l, 16, 0, 0);
}

// ---------------- shared 128x128 MFMA GEMM core ----------------
template<int KB>
__device__ __forceinline__ void gemm_core(const ushort* __restrict__ A, int lda,
                                          const ushort* __restrict__ B, int ldb,
                                          f32x4 acc[4][4]) {
  __shared__ ushort As[128 * 64];
  __shared__ ushort Bs[128 * 64];
  const int tid = threadIdx.x;
  const int lane = tid & 63;
  const int wv = tid >> 6;
  const int wr = (wv >> 1) * 64;
  const int wc = (wv & 1) * 64;
  const int srow = (lane >> 3);
  const int sg = ((lane & 7) ^ (srow & 7)) * 8;
  f32x4 zero = {0.f, 0.f, 0.f, 0.f};
#pragma unroll
  for (int mt = 0; mt < 4; ++mt)
#pragma unroll
    for (int nt = 0; nt < 4; ++nt) acc[mt][nt] = zero;

  for (int kb = 0; kb < KB; ++kb) {
#pragma unroll
    for (int j = 0; j < 4; ++j) {
      int r0 = wv * 32 + j * 8;
      int row = r0 + srow;
      gld16(A + row * lda + kb * 64 + sg, &As[r0 * 64]);
      gld16(B + row * ldb + kb * 64 + sg, &Bs[r0 * 64]);
    }
    __syncthreads();
#pragma unroll
    for (int ks = 0; ks < 2; ++ks) {
      s16x8 af[4], bfr[4];
      const int G = ks * 4 + (lane >> 4);
#pragma unroll
      for (int mt = 0; mt < 4; ++mt) {
        int row = wr + mt * 16 + (lane & 15);
        af[mt] = *(const s16x8*)&As[row * 64 + (G ^ (row & 7)) * 8];
      }
#pragma unroll
      for (int nt = 0; nt < 4; ++nt) {
        int row = wc + nt * 16 + (lane & 15);
        bfr[nt] = *(const s16x8*)&Bs[row * 64 + (G ^ (row & 7)) * 8];
      }
#pragma unroll
      for (int mt = 0; mt < 4; ++mt)
#pragma unroll
        for (int nt = 0; nt < 4; ++nt)
          acc[mt][nt] = __builtin_amdgcn_mfma_f32_16x16x32_bf16(af[mt], bfr[nt], acc[mt][nt], 0, 0, 0);
    }
    __syncthreads();
  }
}

// ---------------- kernel 1: gather + weight casts + permuted bias build ----------------
__global__ __launch_bounds__(256) void k_prep(const float* __restrict__ x,
                                              const float* __restrict__ wqkv,
                                              const float* __restrict__ wout,
                                              const float* __restrict__ w1,
                                              const float* __restrict__ w2,
                                              const float* __restrict__ table,
                                              ushort* __restrict__ Xw,
                                              ushort* __restrict__ wqkvb,
                                              ushort* __restrict__ woutb,
                                              ushort* __restrict__ w1b,
                                              ushort* __restrict__ w2b,
                                              ushort* __restrict__ biasPh) {
  __shared__ ushort smem[64 * 264];
  const int bid = blockIdx.x, tid = threadIdx.x;
  if (bid < 320) {
    ushort (*Ls)[264] = (ushort(*)[264])smem;
    const int t0 = bid * 64;
    const int w = t0 / 640;
    const int tokbase = t0 - w * 640;
    const int b = w >> 4, wh = (w >> 2) & 3, ww = w & 3;
    for (int i = tid; i < 64 * 256; i += 256) {
      int c = i >> 6, tl = i & 63;
      int tok = tokbase + tl;
      ushort val = 0;
      if (tok < 625) {
        int ii = tok / 25, jj = tok - ii * 25;
        val = f2b(x[((b * 256 + c) * 100 + wh * 25 + ii) * 100 + ww * 25 + jj]);
      }
      Ls[tl][c] = val;
    }
    __syncthreads();
    for (int i = tid; i < 64 * 32; i += 256) {
      int tl = i >> 5, g = (i & 31) * 8;
      *(uint4*)(Xw + (t0 + tl) * 256 + g) = *(const uint4*)&Ls[tl][g];
    }
  } else if (bid < 832) {
    int v = (bid - 320) * 1024 + tid * 4;
    const float* src; ushort* dst; int off;
    if (v < 196608)      { src = wqkv; dst = wqkvb; off = v; }
    else if (v < 262144) { src = wout; dst = woutb; off = v - 196608; }
    else if (v < 393216) { src = w1;   dst = w1b;   off = v - 262144; }
    else                 { src = w2;   dst = w2b;   off = v - 393216; }
    float4 f = *(const float4*)(src + off);
    ushort4 u; u.x = f2b(f.x); u.y = f2b(f.y); u.z = f2b(f.z); u.w = f2b(f.w);
    *(ushort4*)(dst + off) = u;
  } else {
    // bias permuted to SWAPPED attn C-frag order (S^T: rows=kv, cols=q),
    // *log2e, kv-mask folded in.  C-frag: lane(quad,cl) reg rr holds
    // C[kv = chunk*16 + quad*4+rr][q = t*16 + cl].
    float* tl = (float*)smem;
    const int qb = bid - 832;
    const int h = qb / 40, t = qb - (qb / 40) * 40;
    for (int i = tid; i < 2401; i += 256) tl[i] = table[i * 8 + h] * 1.4426950408889634f;
    __syncthreads();
    const int lane = tid >> 2, rr = tid & 3;
    const int quad = lane >> 4, cl = lane & 15;
    int qrow = t * 16 + cl;
    int qg = (qrow < 625) ? qrow : 0;
    const int ri = qg / 25, ci = qg - ri * 25;
    for (int cc = 0; cc < 4; ++cc)
      for (int cp = 0; cp < 5; ++cp)
#pragma unroll
        for (int codd = 0; codd < 2; ++codd) {
          int kv = cc * 160 + (cp * 2 + codd) * 16 + quad * 4 + rr;
          float v = -1e30f;
          if (kv < 625) {
            int rj = kv / 25, cj = kv - rj * 25;
            v = tl[(ri - rj + 24) * 49 + (ci - cj + 24)];
          }
          biasPh[((((h * 40 + t) * 4 + cc) * 5 + cp) * 64 + lane) * 8 + codd * 4 + rr] = f2b(v);
        }
  }
}

// ---------------- kernel 2: QKV projection ----------------
__global__ __launch_bounds__(256) void k_qkv(const ushort* __restrict__ Xw,
                                             const ushort* __restrict__ Wb,
                                             ushort* __restrict__ Qb,
                                             ushort* __restrict__ Kb,
                                             ushort* __restrict__ VbT) {
  f32x4 acc[4][4];
  gemm_core<4>(Xw + blockIdx.x * 128 * 256, 256, Wb + blockIdx.y * 128 * 256, 256, acc);
  const int lane = threadIdx.x & 63, wv = threadIdx.x >> 6;
  const int wr = (wv >> 1) * 64, wc = (wv & 1) * 64;
  const int which = blockIdx.y >> 1;
  const float QSC = 0.17677669529663687f * 1.4426950408889634f;
#pragma unroll
  for (int mt = 0; mt < 4; ++mt) {
#pragma unroll
    for (int nt = 0; nt < 4; ++nt) {
      int n = blockIdx.y * 128 + wc + nt * 16 + (lane & 15);
      int h = (n >> 5) & 7, ch = n & 31;
      int m0 = blockIdx.x * 128 + wr + mt * 16 + (lane >> 4) * 4;
      int w = m0 / 640, tok0 = m0 - w * 640;
      if (which == 2) {
        ushort4 pk;
        pk.x = f2b_fast(acc[mt][nt][0]); pk.y = f2b_fast(acc[mt][nt][1]);
        pk.z = f2b_fast(acc[mt][nt][2]); pk.w = f2b_fast(acc[mt][nt][3]);
        *(ushort4*)(VbT + (((w << 3) + h) * 32 + ch) * 640 + tok0) = pk;
      } else {
        ushort* dst = which == 0 ? Qb : Kb;
        float sc = which == 0 ? QSC : 1.f;
#pragma unroll
        for (int r = 0; r < 4; ++r)
          dst[(((w << 3) + h) * 640 + tok0 + r) * 32 + ch] = f2b_fast(acc[mt][nt][r] * sc);
      }
    }
  }
}

// ---------------- kernel 3: fused windowed attention — zero-LDS, depth-first ----------------
// 1280 blocks = 32win x 5tg x 8h (h=bid&7 XCD pin). Each wave owns q-tiles
// t0=tg*8+wv*2 and t0+1, sharing K and V fragments.
// QK^T computed SWAPPED: s = mfma(K, Q, biasT) -> S^T (rows kv, cols q).
// Depth-first per-kc: only 2 K-frags + 2 V-frags + 2 score accs live at a
// time (vs 10/10/10 in R6) -> unified VGPR+AGPR fits 128 -> 4 waves/SIMD.
// P -> PV B-frag in-register: cvt_pk_bf16 + permlane32_swap + permlane16_swap.
// exp2 via __builtin_amdgcn_exp2f (single v_exp_f32; -1e30 mask underflows to 0).
// Row-sums via ones-MFMA.  Output o^T: lane holds 4 consecutive channels.
__global__ __launch_bounds__(256, 4) void k_attn(const ushort* __restrict__ Qb,
                                                 const ushort* __restrict__ Kb,
                                                 const ushort* __restrict__ VbT,
                                                 const ushort* __restrict__ biasPh,
                                                 ushort* __restrict__ AO) {
  const int tid = threadIdx.x;
  const int lane = tid & 63;
  const int wv = tid >> 6;
  const int quad = lane >> 4;
  const int cl = lane & 15;
  const int bid = blockIdx.x;
  const int h = bid & 7;                // XCD pin
  const int rem = bid >> 3;             // 0..159
  const int win = rem / 5;
  const int tg = rem - win * 5;
  const ushort* Qg = Qb + (win * 8 + h) * 20480;
  const ushort* Kg = Kb + (win * 8 + h) * 20480;
  const ushort* Vt = VbT + (win * 8 + h) * 20480;   // [ch][640]

  const int t0 = tg * 8 + wv * 2;
  const s16x8 qf0 = *(const s16x8*)(Qg + (t0 * 16 + cl) * 32 + quad * 8);
  const s16x8 qf1 = *(const s16x8*)(Qg + ((t0 + 1) * 16 + cl) * 32 + quad * 8);
  s16x8 ones;
#pragma unroll
  for (int j = 0; j < 8; ++j) ones[j] = (short)0x3F80;    // bf16 1.0

  const f32x4 zero = {0.f, 0.f, 0.f, 0.f};
  f32x4 o00 = zero, o01 = zero, o10 = zero, o11 = zero;
  f32x4 sum0 = zero, sum1 = zero;

  const ushort* bp0 = biasPh + ((h * 40 + t0) * 20) * 512 + lane * 8;

#pragma unroll
  for (int cc = 0; cc < 4; ++cc) {
#pragma unroll
    for (int kc = 0; kc < 5; ++kc) {
      // 2 K-frags (A of S^T) + 2 V-frags (A of o^T), shared by both q-tiles
      const s16x8 kfA = *(const s16x8*)(Kg + (cc * 160 + (2 * kc) * 16 + cl) * 32 + quad * 8);
      const s16x8 kfB = *(const s16x8*)(Kg + (cc * 160 + (2 * kc + 1) * 16 + cl) * 32 + quad * 8);
      const s16x8 vfa = *(const s16x8*)(Vt + cl * 640 + cc * 160 + kc * 32 + quad * 8);
      const s16x8 vfb = *(const s16x8*)(Vt + (16 + cl) * 640 + cc * 160 + kc * 32 + quad * 8);
#pragma unroll
      for (int tlp = 0; tlp < 2; ++tlp) {
        const s16x8 qf = tlp ? qf1 : qf0;
        // bias C-operand (log2-domain, kv-mask folded, S^T order)
        s16x8 bb = *(const s16x8*)(bp0 + (tlp * 20 + cc * 5 + kc) * 512);
        const unsigned* bw = (const unsigned*)&bb;
        f32x4 c0, c1;
        c0[0] = lo2f(bw[0]); c0[1] = hi2f(bw[0]); c0[2] = lo2f(bw[1]); c0[3] = hi2f(bw[1]);
        c1[0] = lo2f(bw[2]); c1[1] = hi2f(bw[2]); c1[2] = lo2f(bw[3]); c1[3] = hi2f(bw[3]);
        f32x4 s0 = __builtin_amdgcn_mfma_f32_16x16x32_bf16(kfA, qf, c0, 0, 0, 0);
        f32x4 s1 = __builtin_amdgcn_mfma_f32_16x16x32_bf16(kfB, qf, c1, 0, 0, 0);
#pragma unroll
        for (int r = 0; r < 4; ++r) {
          s0[r] = __builtin_amdgcn_exp2f(s0[r]);
          s1[r] = __builtin_amdgcn_exp2f(s1[r]);
        }
        unsigned a0 = cvtpk(s0[0], s0[1]);
        unsigned a1 = cvtpk(s0[2], s0[3]);
        unsigned b0 = cvtpk(s1[0], s1[1]);
        unsigned b1 = cvtpk(s1[2], s1[3]);
        pl32(a0, b0); pl16(a0, b0);       // a0 -> frag word0, b0 -> word2
        pl32(a1, b1); pl16(a1, b1);       // a1 -> word1,      b1 -> word3
        u32x4 pw; pw[0] = a0; pw[1] = a1; pw[2] = b0; pw[3] = b1;
        s16x8 pf = __builtin_bit_cast(s16x8, pw);
        f32x4& o0 = tlp ? o10 : o00;
        f32x4& o1 = tlp ? o11 : o01;
        f32x4& sm = tlp ? sum1 : sum0;
        o0 = __builtin_amdgcn_mfma_f32_16x16x32_bf16(vfa, pf, o0, 0, 0, 0);
        o1 = __builtin_amdgcn_mfma_f32_16x16x32_bf16(vfb, pf, o1, 0, 0, 0);
        sm = __builtin_amdgcn_mfma_f32_16x16x32_bf16(ones, pf, sm, 0, 0, 0);
      }
    }
  }
  // --- normalize + store; o^T rows = channels, cols = q (lane-local sum) ---
#pragma unroll
  for (int tlp = 0; tlp < 2; ++tlp) {
    const f32x4& o0 = tlp ? o10 : o00;
    const f32x4& o1 = tlp ? o11 : o01;
    const f32x4& sm = tlp ? sum1 : sum0;
    int tok = (t0 + tlp) * 16 + cl;
    if (tok < 625) {
      float inv = 1.f / sm[0];
      int base = (win * 640 + tok) * 256 + h * 32 + quad * 4;
      ushort4 p0, p1;
      p0.x = f2b_fast(o0[0] * inv); p0.y = f2b_fast(o0[1] * inv);
      p0.z = f2b_fast(o0[2] * inv); p0.w = f2b_fast(o0[3] * inv);
      p1.x = f2b_fast(o1[0] * inv); p1.y = f2b_fast(o1[1] * inv);
      p1.z = f2b_fast(o1[2] * inv); p1.w = f2b_fast(o1[3] * inv);
      *(ushort4*)(AO + base) = p0;
      *(ushort4*)(AO + base + 16) = p1;
    }
  }
}

// ---------------- kernel 4: out-projection + un-partition + LayerNorm ----------------
__global__ __launch_bounds__(256, 2) void k_out_ln(const ushort* __restrict__ AO,
                                                   const ushort* __restrict__ Wb,
                                                   const float* __restrict__ gamma,
                                                   const float* __restrict__ beta,
                                                   ushort* __restrict__ Yn) {
  __shared__ ushort As[64 * 64];
  __shared__ ushort Bs[256 * 64];
  __shared__ float red[2][64][2];
  const int tid = threadIdx.x;
  const int lane = tid & 63;
  const int wv = tid >> 6;
  const int wr = (wv >> 1) * 32, wc = (wv & 1) * 128;
  const int quad = lane >> 4, cl = lane & 15;
  const int srow = lane >> 3;
  const int sg = ((lane & 7) ^ (srow & 7)) * 8;
  f32x4 zero = {0.f, 0.f, 0.f, 0.f};
  f32x4 acc[2][8];
#pragma unroll
  for (int mt = 0; mt < 2; ++mt)
#pragma unroll
    for (int nt = 0; nt < 8; ++nt) acc[mt][nt] = zero;

  const ushort* A = AO + blockIdx.x * 64 * 256;
  for (int kb = 0; kb < 4; ++kb) {
#pragma unroll
    for (int i = 0; i < 10; ++i) {
      int r0 = (wv + i * 4) * 8;
      int row = r0 + srow;
      if (r0 < 64) gld16(A + row * 256 + kb * 64 + sg, &As[r0 * 64]);
      else         gld16(Wb + (row - 64) * 256 + kb * 64 + sg, &Bs[(r0 - 64) * 64]);
    }
    __syncthreads();
#pragma unroll
    for (int ks = 0; ks < 2; ++ks) {
      s16x8 af[2], bfr[8];
      const int G = ks * 4 + quad;
#pragma unroll
      for (int mt = 0; mt < 2; ++mt) {
        int row = wr + mt * 16 + cl;
        af[mt] = *(const s16x8*)&As[row * 64 + (G ^ (row & 7)) * 8];
      }
#pragma unroll
      for (int nt = 0; nt < 8; ++nt) {
        int row = wc + nt * 16 + cl;
        bfr[nt] = *(const s16x8*)&Bs[row * 64 + (G ^ (row & 7)) * 8];
      }
#pragma unroll
      for (int mt = 0; mt < 2; ++mt)
#pragma unroll
        for (int nt = 0; nt < 8; ++nt)
          acc[mt][nt] = __builtin_amdgcn_mfma_f32_16x16x32_bf16(af[mt], bfr[nt], acc[mt][nt], 0, 0, 0);
    }
    __syncthreads();
  }
#pragma unroll
  for (int mt = 0; mt < 2; ++mt)
#pragma unroll
    for (int r = 0; r < 4; ++r) {
      float s = 0.f, ss = 0.f;
#pragma unroll
      for (int nt = 0; nt < 8; ++nt) { float v = acc[mt][nt][r]; s += v; ss += v * v; }
      s += __shfl_xor(s, 1, 64); ss += __shfl_xor(ss, 1, 64);
      s += __shfl_xor(s, 2, 64); ss += __shfl_xor(ss, 2, 64);
      s += __shfl_xor(s, 4, 64); ss += __shfl_xor(ss, 4, 64);
      s += __shfl_xor(s, 8, 64); ss += __shfl_xor(ss, 8, 64);
      if (cl == 0) {
        int row = wr + mt * 16 + quad * 4 + r;
        red[wc >> 7][row][0] = s;
        red[wc >> 7][row][1] = ss;
      }
    }
  __syncthreads();
  float g[8], bt[8];
#pragma unroll
  for (int nt = 0; nt < 8; ++nt) { int n = wc + nt * 16 + cl; g[nt] = gamma[n]; bt[nt] = beta[n]; }
  const int m0 = blockIdx.x * 64;
#pragma unroll
  for (int mt = 0; mt < 2; ++mt)
#pragma unroll
    for (int r = 0; r < 4; ++r) {
      int row = wr + mt * 16 + quad * 4 + r;
      int m = m0 + row;
      int w = m / 640, tok = m - w * 640;
      if (tok < 625) {
        float sum = red[0][row][0] + red[1][row][0];
        float ssum = red[0][row][1] + red[1][row][1];
        float mean = sum * 0.00390625f;
        float var = ssum * 0.00390625f - mean * mean;
        float rstd = rsqrtf(var + 1e-5f);
        int b = w >> 4, whh = (w >> 2) & 3, www = w & 3;
        int ii = tok / 25, jj = tok - ii * 25;
        int p = (whh * 25 + ii) * 100 + www * 25 + jj;
        ushort* dst = Yn + (b * 10000 + p) * 256;
#pragma unroll
        for (int nt = 0; nt < 8; ++nt) {
          float v = (acc[mt][nt][r] - mean) * rstd * g[nt] + bt[nt];
          dst[wc + nt * 16 + cl] = f2b_fast(v);
        }
      }
    }
}

// ---------------- kernel 5: fc1 + exact GELU ----------------
__global__ __launch_bounds__(256) void k_fc1(const ushort* __restrict__ Yn,
                                             const ushort* __restrict__ W1b,
                                             const float* __restrict__ b1,
                                             ushort* __restrict__ G) {
  f32x4 acc[4][4];
  gemm_core<4>(Yn + blockIdx.x * 128 * 256, 256, W1b + blockIdx.y * 128 * 256, 256, acc);
  const int lane = threadIdx.x & 63, wv = threadIdx.x >> 6;
  const int wr = (wv >> 1) * 64, wc = (wv & 1) * 64;
#pragma unroll
  for (int mt = 0; mt < 4; ++mt)
#pragma unroll
    for (int nt = 0; nt < 4; ++nt) {
      int n = blockIdx.y * 128 + wc + nt * 16 + (lane & 15);
      float bias = b1[n];
#pragma unroll
      for (int r = 0; r < 4; ++r) {
        int m = blockIdx.x * 128 + wr + mt * 16 + (lane >> 4) * 4 + r;
        float v = acc[mt][nt][r] + bias;
        v = 0.5f * v * (1.f + erff(v * 0.70710678118f));
        G[m * 512 + n] = f2b_fast(v);
      }
    }
}

// ---------------- kernel 6: fc2 + residual, swapped roles (M=ch, N=tok) ----------------
__global__ __launch_bounds__(256) void k_fc2(const ushort* __restrict__ W2b,
                                             const ushort* __restrict__ G,
                                             const float* __restrict__ b2,
                                             const float* __restrict__ x,
                                             float* __restrict__ out) {
  f32x4 acc[4][4];
  gemm_core<8>(W2b + blockIdx.x * 128 * 512, 512, G + blockIdx.y * 128 * 512, 512, acc);
  const int lane = threadIdx.x & 63, wv = threadIdx.x >> 6;
  const int wr = (wv >> 1) * 64, wc = (wv & 1) * 64;
#pragma unroll
  for (int mt = 0; mt < 4; ++mt)
#pragma unroll
    for (int nt = 0; nt < 4; ++nt) {
      int t = blockIdx.y * 128 + wc + nt * 16 + (lane & 15);
      if (t < 20000) {
        int b = t / 10000, p = t - b * 10000;
#pragma unroll
        for (int r = 0; r < 4; ++r) {
          int c = blockIdx.x * 128 + wr + mt * 16 + (lane >> 4) * 4 + r;
          int idx = (b * 256 + c) * 10000 + p;
          out[idx] = x[idx] + acc[mt][nt][r] + b2[c];
        }
      }
    }
}

extern "C" void kernel_launch(void* const* d_in, const int* in_sizes, int n_in,
                              void* d_out, int out_size, void* d_ws, size_t ws_size,
                              hipStream_t stream) {
  const float* x     = (const float*)d_in[0];
  const float* wqkv  = (const float*)d_in[1];
  const float* wout  = (const float*)d_in[2];
  const float* bias  = (const float*)d_in[3];
  const float* gamma = (const float*)d_in[4];
  const float* beta  = (const float*)d_in[5];
  const float* w1    = (const float*)d_in[6];
  const float* b1    = (const float*)d_in[7];
  const float* w2    = (const float*)d_in[8];
  const float* b2    = (const float*)d_in[9];
  float* out = (float*)d_out;
  char* ws = (char*)d_ws;

  ushort* Xw    = (ushort*)(ws + 0);
  ushort* AO    = Xw;
  ushort* wqkvb = (ushort*)(ws + 10485760);
  ushort* woutb = (ushort*)(ws + 10878976);
  ushort* w1b   = (ushort*)(ws + 11010048);
  ushort* w2b   = (ushort*)(ws + 11272192);
  ushort* Qb    = (ushort*)(ws + 11534336);
  ushort* Kb    = (ushort*)(ws + 22020096);
  ushort* VbT   = (ushort*)(ws + 32505856);
  ushort* biasPh= (ushort*)(ws + 42991616);
  ushort* Yn    = (ushort*)(ws + 22020096);
  ushort* G     = (ushort*)(ws + 32505856);

  k_prep  <<<1152, 256, 0, stream>>>(x, wqkv, wout, w1, w2, bias,
                                     Xw, wqkvb, woutb, w1b, w2b, biasPh);
  k_qkv   <<<dim3(160, 6), 256, 0, stream>>>(Xw, wqkvb, Qb, Kb, VbT);
  k_attn  <<<1280, 256, 0, stream>>>(Qb, Kb, VbT, biasPh, AO);
  k_out_ln<<<320, 256, 0, stream>>>(AO, woutb, gamma, beta, Yn);
  k_fc1   <<<dim3(157, 4), 256, 0, stream>>>(Yn, w1b, b1, G);
  k_fc2   <<<dim3(2, 157), 256, 0, stream>>>(w2b, G, b2, x, out);
}

// Round 3
// 208.404 us; speedup vs baseline: 1.4359x; 1.0726x over previous
//
#include <hip/hip_runtime.h>

// BEV transformer block, MI355X/gfx950.  Round 8: k_attn 4-tile waves + burst loads.
// R7 post-mortem: halving VALU + regs changed nothing -> latency-bound serial
// chain, not enough in-wave ILP nor TLP.  R8: 128-thread blocks (2 waves),
// 4 q-tiles/wave (K/V loads amortized 2x, 4 independent chains), per-64kv-chunk
// K/V load burst + sched_barrier(0) pin, ones-MFMA row-sum replaced by scalar
// f32 partials + permlane butterfly reduce (-20% MFMA work).
// ws layout (bytes) — regions aliased across kernel lifetimes (peak 53,084,160):
//   [0,10485760)          Xw (k_prep..k_qkv)  then AO (k_attn..k_out_ln)
//   [10485760,11534336)   bf16 weights (all)
//   [11534336,42991616)   Qb/Kb/VbT (k_qkv..k_attn); then Yn (k_out_ln..k_fc1) @22020096
//   [42991616,49545216)   biasPh bf16 C-frag-permuted (k_prep..k_attn)
//   [32505856,53084160)   G (k_fc1..k_fc2) — overlaps VbT/biasPh, disjoint lifetime

using f32x4 = __attribute__((ext_vector_type(4))) float;
using s16x8 = __attribute__((ext_vector_type(8))) short;
using u32x4 = __attribute__((ext_vector_type(4))) unsigned;

__device__ __forceinline__ ushort f2b(float f) {            // RNE (cold paths)
  union { float f; unsigned u; } v; v.f = f;
  return (ushort)((v.u + 0x7FFFu + ((v.u >> 16) & 1u)) >> 16);
}
__device__ __forceinline__ ushort f2b_fast(float f) {       // round-half-up
  union { float f; unsigned u; } v; v.f = f;
  return (ushort)((v.u + 0x8000u) >> 16);
}
__device__ __forceinline__ float b2f(ushort u) {
  union { unsigned u; float f; } v; v.u = ((unsigned)u) << 16; return v.f;
}
__device__ __forceinline__ float lo2f(unsigned w) {
  union { unsigned u; float f; } v; v.u = w << 16; return v.f;
}
__device__ __forceinline__ float hi2f(unsigned w) {
  union { unsigned u; float f; } v; v.u = w & 0xffff0000u; return v.f;
}

__device__ __forceinline__ unsigned cvtpk(float lo, float hi) {
  unsigned r;
  asm("v_cvt_pk_bf16_f32 %0, %1, %2" : "=v"(r) : "v"(lo), "v"(hi));
  return r;
}
// a' = {a[0:31] | b[0:31]},  b' = {a[32:63] | b[32:63]}
__device__ __forceinline__ void pl32(unsigned& a, unsigned& b) {
  asm("v_permlane32_swap_b32 %0, %1" : "+v"(a), "+v"(b));
}
// a' = {a[0:15], b[0:15], a[32:47], b[32:47]},  b' = {a[16:31], b[16:31], a[48:63], b[48:63]}
__device__ __forceinline__ void pl16(unsigned& a, unsigned& b) {
  asm("v_permlane16_swap_b32 %0, %1" : "+v"(a), "+v"(b));
}

__device__ __forceinline__ void gld16(const void* g, void* l) {
  __builtin_amdgcn_global_load_lds((const __attribute__((address_space(1))) void*)g,
                                   (__attribute__((address_space(3))) void*)l, 16, 0, 0);
}

// ---------------- shared 128x128 MFMA GEMM core ----------------
template<int KB>
__device__ __forceinline__ void gemm_core(const ushort* __restrict__ A, int lda,
                                          const ushort* __restrict__ B, int ldb,
                                          f32x4 acc[4][4]) {
  __shared__ ushort As[128 * 64];
  __shared__ ushort Bs[128 * 64];
  const int tid = threadIdx.x;
  const int lane = tid & 63;
  const int wv = tid >> 6;
  const int wr = (wv >> 1) * 64;
  const int wc = (wv & 1) * 64;
  const int srow = (lane >> 3);
  const int sg = ((lane & 7) ^ (srow & 7)) * 8;
  f32x4 zero = {0.f, 0.f, 0.f, 0.f};
#pragma unroll
  for (int mt = 0; mt < 4; ++mt)
#pragma unroll
    for (int nt = 0; nt < 4; ++nt) acc[mt][nt] = zero;

  for (int kb = 0; kb < KB; ++kb) {
#pragma unroll
    for (int j = 0; j < 4; ++j) {
      int r0 = wv * 32 + j * 8;
      int row = r0 + srow;
      gld16(A + row * lda + kb * 64 + sg, &As[r0 * 64]);
      gld16(B + row * ldb + kb * 64 + sg, &Bs[r0 * 64]);
    }
    __syncthreads();
#pragma unroll
    for (int ks = 0; ks < 2; ++ks) {
      s16x8 af[4], bfr[4];
      const int G = ks * 4 + (lane >> 4);
#pragma unroll
      for (int mt = 0; mt < 4; ++mt) {
        int row = wr + mt * 16 + (lane & 15);
        af[mt] = *(const s16x8*)&As[row * 64 + (G ^ (row & 7)) * 8];
      }
#pragma unroll
      for (int nt = 0; nt < 4; ++nt) {
        int row = wc + nt * 16 + (lane & 15);
        bfr[nt] = *(const s16x8*)&Bs[row * 64 + (G ^ (row & 7)) * 8];
      }
#pragma unroll
      for (int mt = 0; mt < 4; ++mt)
#pragma unroll
        for (int nt = 0; nt < 4; ++nt)
          acc[mt][nt] = __builtin_amdgcn_mfma_f32_16x16x32_bf16(af[mt], bfr[nt], acc[mt][nt], 0, 0, 0);
    }
    __syncthreads();
  }
}

// ---------------- kernel 1: gather + weight casts + permuted bias build ----------------
__global__ __launch_bounds__(256) void k_prep(const float* __restrict__ x,
                                              const float* __restrict__ wqkv,
                                              const float* __restrict__ wout,
                                              const float* __restrict__ w1,
                                              const float* __restrict__ w2,
                                              const float* __restrict__ table,
                                              ushort* __restrict__ Xw,
                                              ushort* __restrict__ wqkvb,
                                              ushort* __restrict__ woutb,
                                              ushort* __restrict__ w1b,
                                              ushort* __restrict__ w2b,
                                              ushort* __restrict__ biasPh) {
  __shared__ ushort smem[64 * 264];
  const int bid = blockIdx.x, tid = threadIdx.x;
  if (bid < 320) {
    ushort (*Ls)[264] = (ushort(*)[264])smem;
    const int t0 = bid * 64;
    const int w = t0 / 640;
    const int tokbase = t0 - w * 640;
    const int b = w >> 4, wh = (w >> 2) & 3, ww = w & 3;
    for (int i = tid; i < 64 * 256; i += 256) {
      int c = i >> 6, tl = i & 63;
      int tok = tokbase + tl;
      ushort val = 0;
      if (tok < 625) {
        int ii = tok / 25, jj = tok - ii * 25;
        val = f2b(x[((b * 256 + c) * 100 + wh * 25 + ii) * 100 + ww * 25 + jj]);
      }
      Ls[tl][c] = val;
    }
    __syncthreads();
    for (int i = tid; i < 64 * 32; i += 256) {
      int tl = i >> 5, g = (i & 31) * 8;
      *(uint4*)(Xw + (t0 + tl) * 256 + g) = *(const uint4*)&Ls[tl][g];
    }
  } else if (bid < 832) {
    int v = (bid - 320) * 1024 + tid * 4;
    const float* src; ushort* dst; int off;
    if (v < 196608)      { src = wqkv; dst = wqkvb; off = v; }
    else if (v < 262144) { src = wout; dst = woutb; off = v - 196608; }
    else if (v < 393216) { src = w1;   dst = w1b;   off = v - 262144; }
    else                 { src = w2;   dst = w2b;   off = v - 393216; }
    float4 f = *(const float4*)(src + off);
    ushort4 u; u.x = f2b(f.x); u.y = f2b(f.y); u.z = f2b(f.z); u.w = f2b(f.w);
    *(ushort4*)(dst + off) = u;
  } else {
    // bias permuted to SWAPPED attn C-frag order (S^T: rows=kv, cols=q),
    // *log2e, kv-mask folded in.  C-frag: lane(quad,cl) reg rr holds
    // C[kv = unit*32 + codd*16 + quad*4+rr][q = t*16 + cl], unit = linear kv-32 idx.
    float* tl = (float*)smem;
    const int qb = bid - 832;
    const int h = qb / 40, t = qb - (qb / 40) * 40;
    for (int i = tid; i < 2401; i += 256) tl[i] = table[i * 8 + h] * 1.4426950408889634f;
    __syncthreads();
    const int lane = tid >> 2, rr = tid & 3;
    const int quad = lane >> 4, cl = lane & 15;
    int qrow = t * 16 + cl;
    int qg = (qrow < 625) ? qrow : 0;
    const int ri = qg / 25, ci = qg - ri * 25;
    for (int cc = 0; cc < 4; ++cc)
      for (int cp = 0; cp < 5; ++cp)
#pragma unroll
        for (int codd = 0; codd < 2; ++codd) {
          int kv = cc * 160 + (cp * 2 + codd) * 16 + quad * 4 + rr;
          float v = -1e30f;
          if (kv < 625) {
            int rj = kv / 25, cj = kv - rj * 25;
            v = tl[(ri - rj + 24) * 49 + (ci - cj + 24)];
          }
          biasPh[((((h * 40 + t) * 4 + cc) * 5 + cp) * 64 + lane) * 8 + codd * 4 + rr] = f2b(v);
        }
  }
}

// ---------------- kernel 2: QKV projection ----------------
__global__ __launch_bounds__(256) void k_qkv(const ushort* __restrict__ Xw,
                                             const ushort* __restrict__ Wb,
                                             ushort* __restrict__ Qb,
                                             ushort* __restrict__ Kb,
                                             ushort* __restrict__ VbT) {
  f32x4 acc[4][4];
  gemm_core<4>(Xw + blockIdx.x * 128 * 256, 256, Wb + blockIdx.y * 128 * 256, 256, acc);
  const int lane = threadIdx.x & 63, wv = threadIdx.x >> 6;
  const int wr = (wv >> 1) * 64, wc = (wv & 1) * 64;
  const int which = blockIdx.y >> 1;
  const float QSC = 0.17677669529663687f * 1.4426950408889634f;
#pragma unroll
  for (int mt = 0; mt < 4; ++mt) {
#pragma unroll
    for (int nt = 0; nt < 4; ++nt) {
      int n = blockIdx.y * 128 + wc + nt * 16 + (lane & 15);
      int h = (n >> 5) & 7, ch = n & 31;
      int m0 = blockIdx.x * 128 + wr + mt * 16 + (lane >> 4) * 4;
      int w = m0 / 640, tok0 = m0 - w * 640;
      if (which == 2) {
        ushort4 pk;
        pk.x = f2b_fast(acc[mt][nt][0]); pk.y = f2b_fast(acc[mt][nt][1]);
        pk.z = f2b_fast(acc[mt][nt][2]); pk.w = f2b_fast(acc[mt][nt][3]);
        *(ushort4*)(VbT + (((w << 3) + h) * 32 + ch) * 640 + tok0) = pk;
      } else {
        ushort* dst = which == 0 ? Qb : Kb;
        float sc = which == 0 ? QSC : 1.f;
#pragma unroll
        for (int r = 0; r < 4; ++r)
          dst[(((w << 3) + h) * 640 + tok0 + r) * 32 + ch] = f2b_fast(acc[mt][nt][r] * sc);
      }
    }
  }
}

// ---------------- kernel 3: fused windowed attention — 4 q-tiles/wave, burst loads ----------------
// 1280 blocks x 128 threads = 2 waves; grid = 32win x 5tg x 8h (h=bid&7 XCD pin).
// Wave wv owns q-tiles t0..t0+3, t0 = tg*8 + wv*4  (5tg x 2wv x 4 = 40 exact).
// Per 64-kv chunk: burst-load kf[4] + va[2] + vb[2], sched_barrier(0) pin, then
// 4 independent tlp chains: bias-C -> 4 QK MFMA -> 16 exp2 -> scalar ssum adds
// -> in-register transpose (cvtpk+permlane) -> 4 PV MFMA.  No ones-MFMA:
// denominator = f32 lane partials + permlane32/16 butterfly in epilogue.
// Zero LDS, no syncthreads.
__global__ __launch_bounds__(128, 3) void k_attn(const ushort* __restrict__ Qb,
                                                 const ushort* __restrict__ Kb,
                                                 const ushort* __restrict__ VbT,
                                                 const ushort* __restrict__ biasPh,
                                                 ushort* __restrict__ AO) {
  const int tid = threadIdx.x;
  const int lane = tid & 63;
  const int wv = tid >> 6;              // 0..1
  const int quad = lane >> 4;
  const int cl = lane & 15;
  const int bid = blockIdx.x;
  const int h = bid & 7;                // XCD pin
  const int rem = bid >> 3;             // 0..159
  const int win = rem / 5;
  const int tg = rem - win * 5;
  const ushort* Qg = Qb + (win * 8 + h) * 20480;
  const ushort* Kg = Kb + (win * 8 + h) * 20480;
  const ushort* Vt = VbT + (win * 8 + h) * 20480;   // [ch][640]

  const int t0 = tg * 8 + wv * 4;
  s16x8 qf[4];
#pragma unroll
  for (int tlp = 0; tlp < 4; ++tlp)
    qf[tlp] = *(const s16x8*)(Qg + ((t0 + tlp) * 16 + cl) * 32 + quad * 8);

  const f32x4 zero = {0.f, 0.f, 0.f, 0.f};
  f32x4 o0[4], o1[4];
  float ssum[4];
#pragma unroll
  for (int tlp = 0; tlp < 4; ++tlp) { o0[tlp] = zero; o1[tlp] = zero; ssum[tlp] = 0.f; }

  // bias for (tile t0+tlp, kv-32-unit u): bpB + (tlp*20 + u)*512
  const ushort* bpB = biasPh + ((h * 40 + t0) * 20) * 512 + lane * 8;

  for (int ch2 = 0; ch2 < 10; ++ch2) {          // 64-kv chunks
    // --- burst: 4 K frags (kv 16-slices 4ch2..4ch2+3) + 2 V frag pairs ---
    s16x8 kf[4], va[2], vb[2];
#pragma unroll
    for (int j = 0; j < 4; ++j)
      kf[j] = *(const s16x8*)(Kg + (ch2 * 64 + j * 16 + cl) * 32 + quad * 8);
#pragma unroll
    for (int j = 0; j < 2; ++j) {
      va[j] = *(const s16x8*)(Vt + cl * 640 + ch2 * 64 + j * 32 + quad * 8);
      vb[j] = *(const s16x8*)(Vt + (16 + cl) * 640 + ch2 * 64 + j * 32 + quad * 8);
    }
    __builtin_amdgcn_sched_barrier(0);          // keep the burst issued up-front
#pragma unroll
    for (int tlp = 0; tlp < 4; ++tlp) {
      const s16x8 bb0 = *(const s16x8*)(bpB + (tlp * 20 + 2 * ch2) * 512);
      const s16x8 bb1 = *(const s16x8*)(bpB + (tlp * 20 + 2 * ch2 + 1) * 512);
      const unsigned* w0 = (const unsigned*)&bb0;
      const unsigned* w1 = (const unsigned*)&bb1;
      f32x4 s0, s1, s2, s3;
      s0[0] = lo2f(w0[0]); s0[1] = hi2f(w0[0]); s0[2] = lo2f(w0[1]); s0[3] = hi2f(w0[1]);
      s1[0] = lo2f(w0[2]); s1[1] = hi2f(w0[2]); s1[2] = lo2f(w0[3]); s1[3] = hi2f(w0[3]);
      s2[0] = lo2f(w1[0]); s2[1] = hi2f(w1[0]); s2[2] = lo2f(w1[1]); s2[3] = hi2f(w1[1]);
      s3[0] = lo2f(w1[2]); s3[1] = hi2f(w1[2]); s3[2] = lo2f(w1[3]); s3[3] = hi2f(w1[3]);
      s0 = __builtin_amdgcn_mfma_f32_16x16x32_bf16(kf[0], qf[tlp], s0, 0, 0, 0);
      s1 = __builtin_amdgcn_mfma_f32_16x16x32_bf16(kf[1], qf[tlp], s1, 0, 0, 0);
      s2 = __builtin_amdgcn_mfma_f32_16x16x32_bf16(kf[2], qf[tlp], s2, 0, 0, 0);
      s3 = __builtin_amdgcn_mfma_f32_16x16x32_bf16(kf[3], qf[tlp], s3, 0, 0, 0);
#pragma unroll
      for (int r = 0; r < 4; ++r) {
        s0[r] = __builtin_amdgcn_exp2f(s0[r]);
        s1[r] = __builtin_amdgcn_exp2f(s1[r]);
        s2[r] = __builtin_amdgcn_exp2f(s2[r]);
        s3[r] = __builtin_amdgcn_exp2f(s3[r]);
      }
      ssum[tlp] += ((s0[0] + s0[1]) + (s0[2] + s0[3])) + ((s1[0] + s1[1]) + (s1[2] + s1[3]))
                 + ((s2[0] + s2[1]) + (s2[2] + s2[3])) + ((s3[0] + s3[1]) + (s3[2] + s3[3]));
      // transpose (s0,s1) -> pf0 (kv unit 2ch2), (s2,s3) -> pf1 (unit 2ch2+1)
      unsigned a0 = cvtpk(s0[0], s0[1]);
      unsigned a1 = cvtpk(s0[2], s0[3]);
      unsigned b0 = cvtpk(s1[0], s1[1]);
      unsigned b1 = cvtpk(s1[2], s1[3]);
      pl32(a0, b0); pl16(a0, b0);
      pl32(a1, b1); pl16(a1, b1);
      u32x4 pw0; pw0[0] = a0; pw0[1] = a1; pw0[2] = b0; pw0[3] = b1;
      s16x8 pf0 = __builtin_bit_cast(s16x8, pw0);
      o0[tlp] = __builtin_amdgcn_mfma_f32_16x16x32_bf16(va[0], pf0, o0[tlp], 0, 0, 0);
      o1[tlp] = __builtin_amdgcn_mfma_f32_16x16x32_bf16(vb[0], pf0, o1[tlp], 0, 0, 0);
      unsigned a2 = cvtpk(s2[0], s2[1]);
      unsigned a3 = cvtpk(s2[2], s2[3]);
      unsigned b2 = cvtpk(s3[0], s3[1]);
      unsigned b3 = cvtpk(s3[2], s3[3]);
      pl32(a2, b2); pl16(a2, b2);
      pl32(a3, b3); pl16(a3, b3);
      u32x4 pw1; pw1[0] = a2; pw1[1] = a3; pw1[2] = b2; pw1[3] = b3;
      s16x8 pf1 = __builtin_bit_cast(s16x8, pw1);
      o0[tlp] = __builtin_amdgcn_mfma_f32_16x16x32_bf16(va[1], pf1, o0[tlp], 0, 0, 0);
      o1[tlp] = __builtin_amdgcn_mfma_f32_16x16x32_bf16(vb[1], pf1, o1[tlp], 0, 0, 0);
    }
  }
  // --- denominator: butterfly reduce lane partials across the 4 quad groups ---
#pragma unroll
  for (int tlp = 0; tlp < 4; ++tlp) {
    float s = ssum[tlp];
    unsigned ua = __builtin_bit_cast(unsigned, s), ub = ua;
    pl32(ua, ub);
    s = __builtin_bit_cast(float, ua) + __builtin_bit_cast(float, ub);
    ua = __builtin_bit_cast(unsigned, s); ub = ua;
    pl16(ua, ub);
    s = __builtin_bit_cast(float, ua) + __builtin_bit_cast(float, ub);
    int tok = (t0 + tlp) * 16 + cl;
    if (tok < 625) {
      float inv = 1.f / s;
      int base = (win * 640 + tok) * 256 + h * 32 + quad * 4;
      ushort4 p0, p1;
      p0.x = f2b_fast(o0[tlp][0] * inv); p0.y = f2b_fast(o0[tlp][1] * inv);
      p0.z = f2b_fast(o0[tlp][2] * inv); p0.w = f2b_fast(o0[tlp][3] * inv);
      p1.x = f2b_fast(o1[tlp][0] * inv); p1.y = f2b_fast(o1[tlp][1] * inv);
      p1.z = f2b_fast(o1[tlp][2] * inv); p1.w = f2b_fast(o1[tlp][3] * inv);
      *(ushort4*)(AO + base) = p0;
      *(ushort4*)(AO + base + 16) = p1;
    }
  }
}

// ---------------- kernel 4: out-projection + un-partition + LayerNorm ----------------
__global__ __launch_bounds__(256, 2) void k_out_ln(const ushort* __restrict__ AO,
                                                   const ushort* __restrict__ Wb,
                                                   const float* __restrict__ gamma,
                                                   const float* __restrict__ beta,
                                                   ushort* __restrict__ Yn) {
  __shared__ ushort As[64 * 64];
  __shared__ ushort Bs[256 * 64];
  __shared__ float red[2][64][2];
  const int tid = threadIdx.x;
  const int lane = tid & 63;
  const int wv = tid >> 6;
  const int wr = (wv >> 1) * 32, wc = (wv & 1) * 128;
  const int quad = lane >> 4, cl = lane & 15;
  const int srow = lane >> 3;
  const int sg = ((lane & 7) ^ (srow & 7)) * 8;
  f32x4 zero = {0.f, 0.f, 0.f, 0.f};
  f32x4 acc[2][8];
#pragma unroll
  for (int mt = 0; mt < 2; ++mt)
#pragma unroll
    for (int nt = 0; nt < 8; ++nt) acc[mt][nt] = zero;

  const ushort* A = AO + blockIdx.x * 64 * 256;
  for (int kb = 0; kb < 4; ++kb) {
#pragma unroll
    for (int i = 0; i < 10; ++i) {
      int r0 = (wv + i * 4) * 8;
      int row = r0 + srow;
      if (r0 < 64) gld16(A + row * 256 + kb * 64 + sg, &As[r0 * 64]);
      else         gld16(Wb + (row - 64) * 256 + kb * 64 + sg, &Bs[(r0 - 64) * 64]);
    }
    __syncthreads();
#pragma unroll
    for (int ks = 0; ks < 2; ++ks) {
      s16x8 af[2], bfr[8];
      const int G = ks * 4 + quad;
#pragma unroll
      for (int mt = 0; mt < 2; ++mt) {
        int row = wr + mt * 16 + cl;
        af[mt] = *(const s16x8*)&As[row * 64 + (G ^ (row & 7)) * 8];
      }
#pragma unroll
      for (int nt = 0; nt < 8; ++nt) {
        int row = wc + nt * 16 + cl;
        bfr[nt] = *(const s16x8*)&Bs[row * 64 + (G ^ (row & 7)) * 8];
      }
#pragma unroll
      for (int mt = 0; mt < 2; ++mt)
#pragma unroll
        for (int nt = 0; nt < 8; ++nt)
          acc[mt][nt] = __builtin_amdgcn_mfma_f32_16x16x32_bf16(af[mt], bfr[nt], acc[mt][nt], 0, 0, 0);
    }
    __syncthreads();
  }
#pragma unroll
  for (int mt = 0; mt < 2; ++mt)
#pragma unroll
    for (int r = 0; r < 4; ++r) {
      float s = 0.f, ss = 0.f;
#pragma unroll
      for (int nt = 0; nt < 8; ++nt) { float v = acc[mt][nt][r]; s += v; ss += v * v; }
      s += __shfl_xor(s, 1, 64); ss += __shfl_xor(ss, 1, 64);
      s += __shfl_xor(s, 2, 64); ss += __shfl_xor(ss, 2, 64);
      s += __shfl_xor(s, 4, 64); ss += __shfl_xor(ss, 4, 64);
      s += __shfl_xor(s, 8, 64); ss += __shfl_xor(ss, 8, 64);
      if (cl == 0) {
        int row = wr + mt * 16 + quad * 4 + r;
        red[wc >> 7][row][0] = s;
        red[wc >> 7][row][1] = ss;
      }
    }
  __syncthreads();
  float g[8], bt[8];
#pragma unroll
  for (int nt = 0; nt < 8; ++nt) { int n = wc + nt * 16 + cl; g[nt] = gamma[n]; bt[nt] = beta[n]; }
  const int m0 = blockIdx.x * 64;
#pragma unroll
  for (int mt = 0; mt < 2; ++mt)
#pragma unroll
    for (int r = 0; r < 4; ++r) {
      int row = wr + mt * 16 + quad * 4 + r;
      int m = m0 + row;
      int w = m / 640, tok = m - w * 640;
      if (tok < 625) {
        float sum = red[0][row][0] + red[1][row][0];
        float ssum = red[0][row][1] + red[1][row][1];
        float mean = sum * 0.00390625f;
        float var = ssum * 0.00390625f - mean * mean;
        float rstd = rsqrtf(var + 1e-5f);
        int b = w >> 4, whh = (w >> 2) & 3, www = w & 3;
        int ii = tok / 25, jj = tok - ii * 25;
        int p = (whh * 25 + ii) * 100 + www * 25 + jj;
        ushort* dst = Yn + (b * 10000 + p) * 256;
#pragma unroll
        for (int nt = 0; nt < 8; ++nt) {
          float v = (acc[mt][nt][r] - mean) * rstd * g[nt] + bt[nt];
          dst[wc + nt * 16 + cl] = f2b_fast(v);
        }
      }
    }
}

// ---------------- kernel 5: fc1 + exact GELU ----------------
__global__ __launch_bounds__(256) void k_fc1(const ushort* __restrict__ Yn,
                                             const ushort* __restrict__ W1b,
                                             const float* __restrict__ b1,
                                             ushort* __restrict__ G) {
  f32x4 acc[4][4];
  gemm_core<4>(Yn + blockIdx.x * 128 * 256, 256, W1b + blockIdx.y * 128 * 256, 256, acc);
  const int lane = threadIdx.x & 63, wv = threadIdx.x >> 6;
  const int wr = (wv >> 1) * 64, wc = (wv & 1) * 64;
#pragma unroll
  for (int mt = 0; mt < 4; ++mt)
#pragma unroll
    for (int nt = 0; nt < 4; ++nt) {
      int n = blockIdx.y * 128 + wc + nt * 16 + (lane & 15);
      float bias = b1[n];
#pragma unroll
      for (int r = 0; r < 4; ++r) {
        int m = blockIdx.x * 128 + wr + mt * 16 + (lane >> 4) * 4 + r;
        float v = acc[mt][nt][r] + bias;
        v = 0.5f * v * (1.f + erff(v * 0.70710678118f));
        G[m * 512 + n] = f2b_fast(v);
      }
    }
}

// ---------------- kernel 6: fc2 + residual, swapped roles (M=ch, N=tok) ----------------
__global__ __launch_bounds__(256) void k_fc2(const ushort* __restrict__ W2b,
                                             const ushort* __restrict__ G,
                                             const float* __restrict__ b2,
                                             const float* __restrict__ x,
                                             float* __restrict__ out) {
  f32x4 acc[4][4];
  gemm_core<8>(W2b + blockIdx.x * 128 * 512, 512, G + blockIdx.y * 128 * 512, 512, acc);
  const int lane = threadIdx.x & 63, wv = threadIdx.x >> 6;
  const int wr = (wv >> 1) * 64, wc = (wv & 1) * 64;
#pragma unroll
  for (int mt = 0; mt < 4; ++mt)
#pragma unroll
    for (int nt = 0; nt < 4; ++nt) {
      int t = blockIdx.y * 128 + wc + nt * 16 + (lane & 15);
      if (t < 20000) {
        int b = t / 10000, p = t - b * 10000;
#pragma unroll
        for (int r = 0; r < 4; ++r) {
          int c = blockIdx.x * 128 + wr + mt * 16 + (lane >> 4) * 4 + r;
          int idx = (b * 256 + c) * 10000 + p;
          out[idx] = x[idx] + acc[mt][nt][r] + b2[c];
        }
      }
    }
}

extern "C" void kernel_launch(void* const* d_in, const int* in_sizes, int n_in,
                              void* d_out, int out_size, void* d_ws, size_t ws_size,
                              hipStream_t stream) {
  const float* x     = (const float*)d_in[0];
  const float* wqkv  = (const float*)d_in[1];
  const float* wout  = (const float*)d_in[2];
  const float* bias  = (const float*)d_in[3];
  const float* gamma = (const float*)d_in[4];
  const float* beta  = (const float*)d_in[5];
  const float* w1    = (const float*)d_in[6];
  const float* b1    = (const float*)d_in[7];
  const float* w2    = (const float*)d_in[8];
  const float* b2    = (const float*)d_in[9];
  float* out = (float*)d_out;
  char* ws = (char*)d_ws;

  ushort* Xw    = (ushort*)(ws + 0);
  ushort* AO    = Xw;
  ushort* wqkvb = (ushort*)(ws + 10485760);
  ushort* woutb = (ushort*)(ws + 10878976);
  ushort* w1b   = (ushort*)(ws + 11010048);
  ushort* w2b   = (ushort*)(ws + 11272192);
  ushort* Qb    = (ushort*)(ws + 11534336);
  ushort* Kb    = (ushort*)(ws + 22020096);
  ushort* VbT   = (ushort*)(ws + 32505856);
  ushort* biasPh= (ushort*)(ws + 42991616);
  ushort* Yn    = (ushort*)(ws + 22020096);
  ushort* G     = (ushort*)(ws + 32505856);

  k_prep  <<<1152, 256, 0, stream>>>(x, wqkv, wout, w1, w2, bias,
                                     Xw, wqkvb, woutb, w1b, w2b, biasPh);
  k_qkv   <<<dim3(160, 6), 256, 0, stream>>>(Xw, wqkvb, Qb, Kb, VbT);
  k_attn  <<<1280, 128, 0, stream>>>(Qb, Kb, VbT, biasPh, AO);
  k_out_ln<<<320, 256, 0, stream>>>(AO, woutb, gamma, beta, Yn);
  k_fc1   <<<dim3(157, 4), 256, 0, stream>>>(Yn, w1b, b1, G);
  k_fc2   <<<dim3(2, 157), 256, 0, stream>>>(w2b, G, b2, x, out);
}